// Round 19
// baseline (34.514 us; speedup 1.0000x reference)
//
#include <hip/hip_runtime.h>

#define NBLK 1024
#define SBAT 256
#define SBLK 8

#define CL 24               // outputs per chunk (43 chunks, last=16)
#define HW 8                // warm-up steps (||C||^8 ~ 1e-6 abs, invisible)
#define W  (CL + HW)        // 32 window steps
#define NCH 43              // ceil(NBLK / CL)
#define P  2                // batches per block
#define NSYS (W * P)        // 64 systems per block
#define THREADS (NSYS * 4)  // 256 threads = 4 waves

typedef __attribute__((address_space(3))) void lds_void_t;
typedef const __attribute__((address_space(1))) void glob_void_t;

// Broadcast lane Q (0..3) of each 4-lane quad to all 4: pure VALU DPP.
template <int Q>
__device__ __forceinline__ float bc4(float x) {
  return __int_as_float(__builtin_amdgcn_update_dpp(
      0, __float_as_int(x), Q * 0x55, 0xF, 0xF, true));
}

// Fused solver (r18 base; tail step reordered so the serial chain never
// waits on freshly-issued prefetch loads).
//   B panel staged into Cs via global_load_lds (dense sources); A direct.
//   GJ phase: 64 systems x 4 lanes, quad-DPP Gauss-Jordan ->
//     C_i = A_i^{-1}B_{i-1} (C_0=0), d_i = A_i^{-1}v_i, into LDS.
//   Tail: 16 lanes (2 chains x 8 rows), 32-step recurrence
//     x_i = d_i - C_i x_{i-1}. Step order: fma -> write x -> store out ->
//     read x-vector -> prefetch C/d. The lgkmcnt wait between the x write
//     and the x-vector read now covers only the 4B write (prefetches are a
//     full step old), cutting ~150-300 cyc/step off the serial chain.
//     s_setprio(1) keeps the chain wave ahead of co-resident GJ waves.
//   HW warm-up steps from x=0 absorb the unknown carry (chunk 0 exact).
__global__ __launch_bounds__(THREADS) void pcr_fused(
    const float* __restrict__ A, const float* __restrict__ B,
    const float* __restrict__ v, float* __restrict__ out) {
  __shared__ float Cs[NSYS * 64];   // 16 KB; staged B, then C (chunk-major)
  __shared__ float Ds[NSYS * 8];    // 2 KB
  __shared__ float Xs[P][8];        // per-chain running x vector (64 B)

  const int t  = threadIdx.x;
  const int ch = blockIdx.x >> 7;           // chunk 0..42
  const int b0 = (blockIdx.x & 127) * P;    // batch panel origin
  const int i_first = (ch > 0) ? (ch * CL - HW) : 0;

  const int s_local = t >> 2;              // system 0..63
  const int l = t & 3;                     // lane-in-quad: owns rows 2l,2l+1
  const int iw = s_local >> 1, q = s_local & 1;
  int i = i_first + iw;
  i = (i > NBLK - 1) ? (NBLK - 1) : i;     // clamp top window overhang
  const int b = b0 + q;
  const long sysid = (long)i * SBAT + b;

  {  // ---- stage B panel (16 KB) into Cs via global_load_lds ----
    const int w = t >> 6;
    #pragma unroll
    for (int k = 0; k < 4; ++k) {
      const int m  = w * 256 + k * 64 + (t & 63);  // dest chunk (16B units)
      const int g  = m ^ ((m >> 4) & 7);           // source chunk (swizzled)
      const int sg = g >> 4, cw = g & 15;          // system, chunk-in-system
      const int iws = sg >> 1, qs = sg & 1;
      int is = i_first + iws;
      is = (is > NBLK - 1) ? (NBLK - 1) : is;
      const int ib = (is > 0) ? (is - 1) : 0;      // i==0 frags zeroed below
      const char* src = (const char*)B +
          (((long)ib * SBAT + b0 + qs) * 256 + cw * 16);
      __builtin_amdgcn_global_load_lds(
          (glob_void_t*)src,
          (lds_void_t*)((char*)Cs + w * 4096 + k * 1024), 16, 0, 0);
    }
  }

  float a[2][8], c[2][8], vv[2];
  {  // direct A load (scattered; sits in the vmcnt queue under the stage)
    const float4* A4 = (const float4*)(A + sysid * 64 + l * 16);
    #pragma unroll
    for (int k = 0; k < 4; ++k) {
      const float4 x4 = A4[k];
      const int m = k >> 1, c0 = (k & 1) * 4;
      a[m][c0+0]=x4.x; a[m][c0+1]=x4.y; a[m][c0+2]=x4.z; a[m][c0+3]=x4.w;
    }
  }
  {
    const float2 x2 = *(const float2*)(v + (long)b * (NBLK * SBLK) + i * SBLK + 2 * l);
    vv[0] = x2.x; vv[1] = x2.y;
  }

  asm volatile("s_waitcnt vmcnt(0)" ::: "memory");  // staged B (and A,v) ready

  {  // B fragment read from staged LDS (swizzled; own wave's quarter only)
    #pragma unroll
    for (int j = 0; j < 4; ++j) {
      const int g = (s_local << 4) + (l << 2) + j;
      const int m = g ^ ((g >> 4) & 7);
      const float4 x4 = *(const float4*)((const char*)Cs + m * 16);
      const int mm = j >> 1, c0 = (j & 1) * 4;
      c[mm][c0+0]=x4.x; c[mm][c0+1]=x4.y; c[mm][c0+2]=x4.z; c[mm][c0+3]=x4.w;
    }
    if (i == 0) {
      #pragma unroll
      for (int m = 0; m < 2; ++m)
        #pragma unroll
        for (int j = 0; j < 8; ++j) c[m][j] = 0.f;
    }
  }

  __syncthreads();   // all frag reads done before any C write below

  {  // ---------------- GJ phase ----------------
#define GJSTEP(K)                                                       \
    {                                                                   \
      constexpr int ol = (K) >> 1;   /* owner lane in quad */           \
      constexpr int mp = (K) & 1;    /* pivot row within owner */       \
      const bool mine = (l == ol);                                      \
      const float invp = 1.0f / a[mp][(K)];                             \
      const float s = mine ? invp : 1.0f;                               \
      _Pragma("unroll")                                                 \
      for (int j = (K) + 1; j < 8; ++j) a[mp][j] *= s;                  \
      _Pragma("unroll")                                                 \
      for (int j = 0; j < 8; ++j) c[mp][j] *= s;                        \
      vv[mp] *= s;                                                      \
      float pa[8], pc[8], pv;                                           \
      _Pragma("unroll")                                                 \
      for (int j = (K) + 1; j < 8; ++j) pa[j] = bc4<ol>(a[mp][j]);      \
      _Pragma("unroll")                                                 \
      for (int j = 0; j < 8; ++j) pc[j] = bc4<ol>(c[mp][j]);            \
      pv = bc4<ol>(vv[mp]);                                             \
      _Pragma("unroll")                                                 \
      for (int m = 0; m < 2; ++m) {                                     \
        float f = a[m][(K)];                                            \
        if (m == mp) f = mine ? 0.0f : f;                               \
        _Pragma("unroll")                                               \
        for (int j = (K) + 1; j < 8; ++j)                               \
          a[m][j] = fmaf(-f, pa[j], a[m][j]);                           \
        _Pragma("unroll")                                               \
        for (int j = 0; j < 8; ++j)                                     \
          c[m][j] = fmaf(-f, pc[j], c[m][j]);                           \
        vv[m] = fmaf(-f, pv, vv[m]);                                    \
      }                                                                 \
    }

    GJSTEP(0) GJSTEP(1) GJSTEP(2) GJSTEP(3)
    GJSTEP(4) GJSTEP(5) GJSTEP(6) GJSTEP(7)
#undef GJSTEP

    {  // C rows -> LDS: chunk k of thread t at (k*THREADS+t)*16 ->
       // every full-wave b128 store is contiguous (conflict-free).
      #pragma unroll
      for (int k = 0; k < 4; ++k) {
        const int m = k >> 1, c0 = (k & 1) * 4;
        *(float4*)((char*)Cs + ((k * THREADS + t) * 16)) =
            make_float4(c[m][c0+0], c[m][c0+1], c[m][c0+2], c[m][c0+3]);
      }
      *(float2*)((char*)Ds + t * 8) = make_float2(vv[0], vv[1]);
    }
  }

  __syncthreads();
  if (t >= P * 8) return;   // 16 lanes run the recurrence; rest exit

  {  // ---------------- serial phase ----------------
    const int sq = t >> 3, sr = t & 7;        // batch-in-panel, row
    const int lq = sr >> 1, m = sr & 1;       // owning GJ lane, row-in-lane
    float* const ob = out + (long)(b0 + sq) * (NBLK * SBLK);
    const int o_lo = ch * CL;
    const int o_hi = (o_lo + CL > NBLK) ? NBLK : (o_lo + CL);

    __builtin_amdgcn_s_setprio(1);   // chain wave beats co-resident GJ waves

#define TLOAD(S, LO, HI, DD)                                              \
    {                                                                     \
      const int gt = (S) * 4 * P + sq * 4 + lq;                           \
      LO = *(const float4*)((const char*)Cs + (((2*m  ) * THREADS + gt) * 16)); \
      HI = *(const float4*)((const char*)Cs + (((2*m+1) * THREADS + gt) * 16)); \
      DD = Ds[((S) * P + sq) * 8 + sr];                                   \
    }
    // Step: fma (uses xlo/xhi from prev read) -> write x -> out-store ->
    // read x-vector. Prefetch is issued AFTER the read (see loop), so the
    // write->read lgkmcnt wait never drains fresh loads.
#define FMASTEP(LO, HI, DD, II)                                           \
    {                                                                     \
      float acc0 = LO.x * xlo.x;                                          \
      acc0 = fmaf(LO.y, xlo.y, acc0);                                     \
      acc0 = fmaf(LO.z, xlo.z, acc0);                                     \
      acc0 = fmaf(LO.w, xlo.w, acc0);                                     \
      float acc1 = HI.x * xhi.x;                                          \
      acc1 = fmaf(HI.y, xhi.y, acc1);                                     \
      acc1 = fmaf(HI.z, xhi.z, acc1);                                     \
      acc1 = fmaf(HI.w, xhi.w, acc1);                                     \
      const float x = DD - acc0 - acc1;                                   \
      Xs[sq][sr] = x;                                                     \
      const int ia = i_first + (II);                                      \
      if (ia >= o_lo && ia < o_hi) ob[ia * SBLK + sr] = x;                \
      xlo = *(const float4*)&Xs[sq][0];                                   \
      xhi = *(const float4*)&Xs[sq][4];                                   \
    }

    float4 xlo = make_float4(0.f, 0.f, 0.f, 0.f);
    float4 xhi = xlo;
    float4 loA, hiA, loB, hiB;
    float  ddA, ddB;
    TLOAD(0, loA, hiA, ddA);
    TLOAD(1, loB, hiB, ddB);
    #pragma unroll
    for (int ii = 0; ii < W; ii += 2) {
      FMASTEP(loA, hiA, ddA, ii);
      if (ii + 2 < W) TLOAD(ii + 2, loA, hiA, ddA);
      FMASTEP(loB, hiB, ddB, ii + 1);
      if (ii + 3 < W) TLOAD(ii + 3, loB, hiB, ddB);
    }
#undef TLOAD
#undef FMASTEP

    __builtin_amdgcn_s_setprio(0);
  }
}

extern "C" void kernel_launch(void* const* d_in, const int* in_sizes, int n_in,
                              void* d_out, int out_size, void* d_ws, size_t ws_size,
                              hipStream_t stream) {
  const float* A = (const float*)d_in[0];
  const float* B = (const float*)d_in[1];
  const float* v = (const float*)d_in[2];
  float* out = (float*)d_out;

  pcr_fused<<<NCH * (SBAT / P), THREADS, 0, stream>>>(A, B, v, out);
}